// Round 5
// baseline (263.077 us; speedup 1.0000x reference)
//
#include <hip/hip_runtime.h>

#define NB 4
#define SEQ 4096
#define DM 512
#define DA 64

typedef __attribute__((ext_vector_type(8))) short bf16x8;
typedef __attribute__((ext_vector_type(4))) float f32x4;
typedef __attribute__((address_space(3))) unsigned int lds_u32;
typedef const __attribute__((address_space(1))) unsigned int glb_u32;

__device__ __forceinline__ unsigned short f2bf(float f) {
  unsigned u = __float_as_uint(f);
  u += 0x7fffu + ((u >> 16) & 1u);
  return (unsigned short)(u >> 16);
}

__device__ __forceinline__ float bf2f(unsigned short h) {
  return __uint_as_float(((unsigned)h) << 16);
}

__device__ __forceinline__ unsigned cvt_pk_bf16(float lo, float hi) {
  unsigned r;
  asm("v_cvt_pk_bf16_f32 %0, %1, %2" : "=v"(r) : "v"(lo), "v"(hi));
  return r;
}

__device__ __forceinline__ void g2lds16(const unsigned short* g, unsigned short* l) {
  __builtin_amdgcn_global_load_lds((glb_u32*)g, (lds_u32*)l, 16, 0, 0);
}

// ---------------- Kernel 1: cast x (f32) -> xb (bf16) ----------------
__global__ void cast_x_kernel(const float* __restrict__ x, unsigned short* __restrict__ xb) {
  size_t i = ((size_t)blockIdx.x * blockDim.x + threadIdx.x) * 4;
  float4 v = *(const float4*)(x + i);
  ushort4 o;
  o.x = f2bf(v.x); o.y = f2bf(v.y); o.z = f2bf(v.z); o.w = f2bf(v.w);
  *(ushort4*)(xb + i) = o;
}

// ------------- Kernel 2: build Wt[640][512] bf16 (transposed) + bias[640] -------------
__global__ void prep_w_kernel(const float* __restrict__ Wq, const float* __restrict__ bq,
                              const float* __restrict__ Wk, const float* __restrict__ bk,
                              const float* __restrict__ Wv, const float* __restrict__ bv,
                              unsigned short* __restrict__ Wt, float* __restrict__ bias) {
  int n = blockIdx.x;  // 0..639
  for (int k = threadIdx.x; k < DM; k += blockDim.x) {
    float w;
    if (n < 64)       w = Wq[(size_t)k * DA + n];
    else if (n < 128) w = Wk[(size_t)k * DA + (n - 64)];
    else              w = Wv[(size_t)k * DM + (n - 128)];
    Wt[(size_t)n * DM + k] = f2bf(w);
  }
  if (threadIdx.x == 0)
    bias[n] = (n < 64) ? bq[n] : (n < 128) ? bk[n - 64] : bv[n - 128];
}

// ------------- Kernel 3: projection GEMM with LDS-repacked coalesced stores -------------
// n<64 -> q[S][64], n<128 -> k[S][64], else vt[512][S] (V^T, keys permuted per 32-chunk)
__launch_bounds__(256)
__global__ void proj_kernel(const unsigned short* __restrict__ xb,
                            const unsigned short* __restrict__ Wt,
                            const float* __restrict__ bias,
                            unsigned short* __restrict__ qws,
                            unsigned short* __restrict__ kws,
                            unsigned short* __restrict__ vt) {
  int ctb = blockIdx.x;
  int rtb = blockIdx.y;
  int tid = threadIdx.x;
  int wid = tid >> 6, lane = tid & 63;
  int g = lane >> 4, c15 = lane & 15;
  int wr = wid >> 1, wc = wid & 1;
  int rbase = rtb * 64 + wr * 32;
  int cbase = ctb * 64 + wc * 32;

  __shared__ unsigned short tile[64][72];   // 9.2KB, padded stride

  f32x4 acc[2][2];
  for (int i = 0; i < 2; i++) for (int j = 0; j < 2; j++) acc[i][j] = (f32x4)0.0f;

  for (int kk = 0; kk < DM; kk += 32) {
    bf16x8 a[2], bb[2];
    for (int i = 0; i < 2; i++)
      a[i] = *(const bf16x8*)(xb + (size_t)(rbase + i * 16 + c15) * DM + kk + g * 8);
    for (int j = 0; j < 2; j++)
      bb[j] = *(const bf16x8*)(Wt + (size_t)(cbase + j * 16 + c15) * DM + kk + g * 8);
    for (int i = 0; i < 2; i++)
      for (int j = 0; j < 2; j++)
        acc[i][j] = __builtin_amdgcn_mfma_f32_16x16x32_bf16(a[i], bb[j], acc[i][j], 0, 0, 0);
  }

  for (int i = 0; i < 2; i++)
    for (int j = 0; j < 2; j++) {
      int n = cbase + j * 16 + c15;
      float bv_ = bias[n];
      for (int r = 0; r < 4; r++) {
        int sl = wr * 32 + i * 16 + g * 4 + r;
        int cl = wc * 32 + j * 16 + c15;
        tile[sl][cl] = f2bf(acc[i][j][r] + bv_);
      }
    }
  __syncthreads();

  int R0 = rtb * 64;
  if (ctb < 2) {
    unsigned short* dst = (ctb == 0) ? qws : kws;
    for (int q = 0; q < 2; q++) {
      int rid = q * 256 + tid;
      int sl = rid >> 3, grp = rid & 7;
      bf16x8 vdat = *(const bf16x8*)&tile[sl][grp * 8];
      *(bf16x8*)(dst + (size_t)(R0 + sl) * DA + grp * 8) = vdat;
    }
  } else {
    int bb_ = R0 >> 12, sb = R0 & (SEQ - 1);
    for (int q = 0; q < 2; q++) {
      int rid = q * 256 + tid;
      int dvl = rid >> 3, sub = rid & 7, chunk = sub >> 2, gg = sub & 3;
      union { unsigned short u[8]; bf16x8 h8; } pk;
      for (int j = 0; j < 8; j++) {
        int keyc = (j < 4) ? (4 * gg + j) : (16 + 4 * gg + (j - 4));
        pk.u[j] = tile[chunk * 32 + keyc][dvl];
      }
      int dv = ctb * 64 - 128 + dvl;
      *(bf16x8*)(vt + ((size_t)bb_ * DM + dv) * SEQ + sb + chunk * 32 + gg * 8) = pk.h8;
    }
  }
}

// ------------- Kernel 4: causal flash attention, LDS-staged, 32 rows/wave -------------
// Grid (8,64): x=(b,dh); y->qblk paired long/short. Block 256 thr = 4 waves =
// (rh: 32-row half) x (wc: 128-dv half). KVBLK=32, dbuf LDS 40KB.
__launch_bounds__(256, 2)
__global__ void attn_kernel(const unsigned short* __restrict__ qws,
                            const unsigned short* __restrict__ kws,
                            const unsigned short* __restrict__ vt,
                            unsigned short* __restrict__ ob16) {
  int bd = blockIdx.x;
  int b = bd >> 1, dh = bd & 1;
  int y = blockIdx.y;
  int qblk = (y < 32) ? y : 95 - y;
  int qb = qblk * 64;
  int tid = threadIdx.x;
  int wid = tid >> 6, lane = tid & 63;
  int g = lane >> 4, c15 = lane & 15;
  int rh = wid & 1, wc = wid >> 1;
  int qrow32 = qb + rh * 32;
  int dvb = dh * 256 + wc * 128;
  int wc128 = wc * 128;
  int qsrc = (g << 4) | (g << 2);

  // per buffer: V[256][32] = 8192 ush, K[32][64] = 2048 ush -> 10240 ush; x2 = 40KB
  __shared__ unsigned short lds[20480];

  size_t bO = (size_t)b * DM + dh * 256;   // vt row base
  size_t bS = (size_t)b * SEQ;

  auto stage = [&](int t, int kt) {
    unsigned short* Vb = &lds[t * 10240];
    unsigned short* Kb = &lds[t * 10240 + 8192];
    for (int r = 0; r < 4; r++) {
      int row = r * 64 + (tid >> 2);
      int colsw = (tid & 3) ^ ((row >> 2) & 3);
      g2lds16(vt + (bO + row) * SEQ + kt + colsw * 8, &Vb[(r * 64 + wid * 16) * 32]);
    }
    {
      int row = tid >> 3;
      int colsw = (tid & 7) ^ (row & 7);
      g2lds16(kws + (bS + kt + row) * DA + colsw * 8, &Kb[wid * 512]);
    }
  };

  bf16x8 qf[2][2];
  for (int t2 = 0; t2 < 2; t2++)
    for (int kc2 = 0; kc2 < 2; kc2++)
      qf[t2][kc2] = *(const bf16x8*)(qws + (bS + qrow32 + t2 * 16 + c15) * DA + kc2 * 32 + g * 8);

  f32x4 acc[2][8];
  for (int t2 = 0; t2 < 2; t2++)
    for (int n = 0; n < 8; n++) acc[t2][n] = (f32x4)0.0f;
  float m_run[2] = {-1e30f, -1e30f}, l_run[2] = {0.0f, 0.0f};

  int nkt = 2 * qblk + 2;

  stage(0, 0);
  __syncthreads();
  int t = 0;
  for (int i = 0; i < nkt; i++) {
    int kt = i * 32;
    if (i + 1 < nkt) stage(t ^ 1, kt + 32);
    const unsigned short* Vb = &lds[t * 10240];
    const unsigned short* Kb = &lds[t * 10240 + 8192];

    // ---- S^T: 32 keys x 32 q-rows (2 tiles) ----
    f32x4 sc[2][2];
    sc[0][0] = (f32x4)0.0f; sc[0][1] = (f32x4)0.0f;
    sc[1][0] = (f32x4)0.0f; sc[1][1] = (f32x4)0.0f;
#pragma unroll
    for (int kc2 = 0; kc2 < 2; kc2++)
#pragma unroll
      for (int ct = 0; ct < 2; ct++) {
        int row = ct * 16 + c15;
        bf16x8 kf = *(const bf16x8*)&Kb[row * 64 + (((kc2 << 2) | g) ^ (row & 7)) * 8];
        sc[0][ct] = __builtin_amdgcn_mfma_f32_16x16x32_bf16(kf, qf[0][kc2], sc[0][ct], 0, 0, 0);
        sc[1][ct] = __builtin_amdgcn_mfma_f32_16x16x32_bf16(kf, qf[1][kc2], sc[1][ct], 0, 0, 0);
      }

    if (i >= nkt - 2) {
#pragma unroll
      for (int t2 = 0; t2 < 2; t2++) {
        int qrow = qrow32 + t2 * 16 + c15;
#pragma unroll
        for (int ct = 0; ct < 2; ct++)
#pragma unroll
          for (int r = 0; r < 4; r++)
            if (kt + ct * 16 + 4 * g + r > qrow) sc[t2][ct][r] = -1e30f;
      }
    }

    // ---- softmax + PV A-frag pack, per row-tile ----
    bf16x8 pa[2];
#pragma unroll
    for (int t2 = 0; t2 < 2; t2++) {
      float mv = -1e30f;
#pragma unroll
      for (int ct = 0; ct < 2; ct++)
#pragma unroll
        for (int r = 0; r < 4; r++) mv = fmaxf(mv, sc[t2][ct][r]);
      mv = fmaxf(mv, __shfl_xor(mv, 16));
      mv = fmaxf(mv, __shfl_xor(mv, 32));
      float mn = fmaxf(m_run[t2], mv);
      float sum = 0.0f;
#pragma unroll
      for (int ct = 0; ct < 2; ct++)
#pragma unroll
        for (int r = 0; r < 4; r++) {
          float p = __expf(sc[t2][ct][r] - mn);
          sc[t2][ct][r] = p;
          sum += p;
        }
      sum += __shfl_xor(sum, 16);
      sum += __shfl_xor(sum, 32);
      float scl = __expf(m_run[t2] - mn);
      m_run[t2] = mn;
      l_run[t2] = l_run[t2] * scl + sum;
      float s0 = __shfl(scl, qsrc), s1 = __shfl(scl, qsrc + 1);
      float s2 = __shfl(scl, qsrc + 2), s3 = __shfl(scl, qsrc + 3);
#pragma unroll
      for (int n = 0; n < 8; n++) {
        acc[t2][n][0] *= s0; acc[t2][n][1] *= s1;
        acc[t2][n][2] *= s2; acc[t2][n][3] *= s3;
      }
      union { int i4[4]; bf16x8 h; } pu;
      pu.i4[0] = cvt_pk_bf16(sc[t2][0][0], sc[t2][0][1]);
      pu.i4[1] = cvt_pk_bf16(sc[t2][0][2], sc[t2][0][3]);
      pu.i4[2] = cvt_pk_bf16(sc[t2][1][0], sc[t2][1][1]);
      pu.i4[3] = cvt_pk_bf16(sc[t2][1][2], sc[t2][1][3]);
      pa[t2] = pu.h;
    }

    // ---- PV: both row-tiles share each V read ----
#pragma unroll
    for (int n = 0; n < 8; n++) {
      int row = wc128 + n * 16 + c15;
      bf16x8 vb = *(const bf16x8*)&Vb[row * 32 + (g ^ ((row >> 2) & 3)) * 8];
      acc[0][n] = __builtin_amdgcn_mfma_f32_16x16x32_bf16(pa[0], vb, acc[0][n], 0, 0, 0);
      acc[1][n] = __builtin_amdgcn_mfma_f32_16x16x32_bf16(pa[1], vb, acc[1][n], 0, 0, 0);
    }
    __syncthreads();
    t ^= 1;
  }

  // ---- epilogue: O = acc / l, bf16 ----
#pragma unroll
  for (int t2 = 0; t2 < 2; t2++) {
    float inv[4];
#pragma unroll
    for (int r = 0; r < 4; r++) inv[r] = 1.0f / __shfl(l_run[t2], qsrc + r);
#pragma unroll
    for (int n = 0; n < 8; n++)
#pragma unroll
      for (int r = 0; r < 4; r++)
        ob16[(bS + qrow32 + t2 * 16 + 4 * g + r) * DM + dvb + n * 16 + c15] =
            f2bf(acc[t2][n][r] * inv[r]);
  }
}

// ------------- Kernel 5: residual + LayerNorm (wave per row, bf16 o) -------------
__launch_bounds__(256)
__global__ void ln_kernel(const float* __restrict__ x, const unsigned short* __restrict__ o,
                          const float* __restrict__ gamma, const float* __restrict__ beta,
                          float* __restrict__ out) {
  int wid = threadIdx.x >> 6, lane = threadIdx.x & 63;
  size_t row = (size_t)blockIdx.x * 4 + wid;
  size_t base = row * DM + lane * 8;
  float4 xa = *(const float4*)(x + base);
  float4 xb2 = *(const float4*)(x + base + 4);
  bf16x8 ov = *(const bf16x8*)(o + base);
  float y[8] = {xa.x + bf2f((unsigned short)ov[0]), xa.y + bf2f((unsigned short)ov[1]),
                xa.z + bf2f((unsigned short)ov[2]), xa.w + bf2f((unsigned short)ov[3]),
                xb2.x + bf2f((unsigned short)ov[4]), xb2.y + bf2f((unsigned short)ov[5]),
                xb2.z + bf2f((unsigned short)ov[6]), xb2.w + bf2f((unsigned short)ov[7])};
  float s1 = 0.0f, s2 = 0.0f;
  for (int j = 0; j < 8; j++) { s1 += y[j]; s2 += y[j] * y[j]; }
  for (int m = 1; m < 64; m <<= 1) { s1 += __shfl_xor(s1, m); s2 += __shfl_xor(s2, m); }
  float mu = s1 * (1.0f / DM);
  float var = s2 * (1.0f / DM) - mu * mu;
  float rs = rsqrtf(var + 1e-5f);
  int c = lane * 8;
  for (int j = 0; j < 8; j++)
    out[base + j] = (y[j] - mu) * rs * gamma[c + j] + beta[c + j];
}

extern "C" void kernel_launch(void* const* d_in, const int* in_sizes, int n_in,
                              void* d_out, int out_size, void* d_ws, size_t ws_size,
                              hipStream_t stream) {
  const float* x     = (const float*)d_in[0];
  const float* Wq    = (const float*)d_in[1];
  const float* bq    = (const float*)d_in[2];
  const float* Wk    = (const float*)d_in[3];
  const float* bk    = (const float*)d_in[4];
  const float* Wv    = (const float*)d_in[5];
  const float* bv    = (const float*)d_in[6];
  const float* gamma = (const float*)d_in[7];
  const float* beta  = (const float*)d_in[8];
  float* out = (float*)d_out;

  char* ws = (char*)d_ws;
  // ob16 (bf16, 16MB) aliases xb (bf16, 16MB): xb dead before attn writes o.
  unsigned short* xb   = (unsigned short*)(ws + 0);
  unsigned short* ob16 = (unsigned short*)(ws + 0);
  unsigned short* qws  = (unsigned short*)(ws + 16777216);
  unsigned short* kws  = (unsigned short*)(ws + 18874368);
  unsigned short* vt   = (unsigned short*)(ws + 20971520);
  unsigned short* Wt   = (unsigned short*)(ws + 37748736);
  float*          bias = (float*)(ws + 38404096);

  cast_x_kernel<<<8192, 256, 0, stream>>>(x, xb);
  prep_w_kernel<<<640, 256, 0, stream>>>(Wq, bq, Wk, bk, Wv, bv, Wt, bias);
  proj_kernel<<<dim3(10, 256), 256, 0, stream>>>(xb, Wt, bias, qws, kws, vt);
  attn_kernel<<<dim3(8, 64), 256, 0, stream>>>(qws, kws, vt, ob16);
  ln_kernel<<<4096, 256, 0, stream>>>(x, ob16, gamma, beta, out);
}

// Round 6
// 223.296 us; speedup vs baseline: 1.1782x; 1.1782x over previous
//
#include <hip/hip_runtime.h>

#define NB 4
#define SEQ 4096
#define DM 512
#define DA 64

typedef __attribute__((ext_vector_type(8))) short bf16x8;
typedef __attribute__((ext_vector_type(4))) float f32x4;
typedef __attribute__((address_space(3))) unsigned int lds_u32;
typedef const __attribute__((address_space(1))) unsigned int glb_u32;

__device__ __forceinline__ unsigned short f2bf(float f) {
  unsigned u = __float_as_uint(f);
  u += 0x7fffu + ((u >> 16) & 1u);
  return (unsigned short)(u >> 16);
}

__device__ __forceinline__ float bf2f(unsigned short h) {
  return __uint_as_float(((unsigned)h) << 16);
}

__device__ __forceinline__ unsigned cvt_pk_bf16(float lo, float hi) {
  unsigned r;
  asm("v_cvt_pk_bf16_f32 %0, %1, %2" : "=v"(r) : "v"(lo), "v"(hi));
  return r;
}

__device__ __forceinline__ void g2lds16(const unsigned short* g, unsigned short* l) {
  __builtin_amdgcn_global_load_lds((glb_u32*)g, (lds_u32*)l, 16, 0, 0);
}

// ---------------- Kernel 1: cast x (f32) -> xb (bf16) ----------------
__global__ void cast_x_kernel(const float* __restrict__ x, unsigned short* __restrict__ xb) {
  size_t i = ((size_t)blockIdx.x * blockDim.x + threadIdx.x) * 4;
  float4 v = *(const float4*)(x + i);
  ushort4 o;
  o.x = f2bf(v.x); o.y = f2bf(v.y); o.z = f2bf(v.z); o.w = f2bf(v.w);
  *(ushort4*)(xb + i) = o;
}

// ------------- Kernel 2: build Wt[640][512] bf16 (transposed) + bias[640] -------------
__global__ void prep_w_kernel(const float* __restrict__ Wq, const float* __restrict__ bq,
                              const float* __restrict__ Wk, const float* __restrict__ bk,
                              const float* __restrict__ Wv, const float* __restrict__ bv,
                              unsigned short* __restrict__ Wt, float* __restrict__ bias) {
  int n = blockIdx.x;  // 0..639
  for (int k = threadIdx.x; k < DM; k += blockDim.x) {
    float w;
    if (n < 64)       w = Wq[(size_t)k * DA + n];
    else if (n < 128) w = Wk[(size_t)k * DA + (n - 64)];
    else              w = Wv[(size_t)k * DM + (n - 128)];
    Wt[(size_t)n * DM + k] = f2bf(w);
  }
  if (threadIdx.x == 0)
    bias[n] = (n < 64) ? bq[n] : (n < 128) ? bk[n - 64] : bv[n - 128];
}

// ------------- Kernel 3: projection GEMM with LDS-repacked coalesced stores -------------
// n<64 -> q[S][64], n<128 -> k[S][64], else vt[512][S] (V^T, keys permuted per 32-chunk)
__launch_bounds__(256)
__global__ void proj_kernel(const unsigned short* __restrict__ xb,
                            const unsigned short* __restrict__ Wt,
                            const float* __restrict__ bias,
                            unsigned short* __restrict__ qws,
                            unsigned short* __restrict__ kws,
                            unsigned short* __restrict__ vt) {
  int ctb = blockIdx.x;
  int rtb = blockIdx.y;
  int tid = threadIdx.x;
  int wid = tid >> 6, lane = tid & 63;
  int g = lane >> 4, c15 = lane & 15;
  int wr = wid >> 1, wc = wid & 1;
  int rbase = rtb * 64 + wr * 32;
  int cbase = ctb * 64 + wc * 32;

  __shared__ unsigned short tile[64][72];

  f32x4 acc[2][2];
  for (int i = 0; i < 2; i++) for (int j = 0; j < 2; j++) acc[i][j] = (f32x4)0.0f;

  for (int kk = 0; kk < DM; kk += 32) {
    bf16x8 a[2], bb[2];
    for (int i = 0; i < 2; i++)
      a[i] = *(const bf16x8*)(xb + (size_t)(rbase + i * 16 + c15) * DM + kk + g * 8);
    for (int j = 0; j < 2; j++)
      bb[j] = *(const bf16x8*)(Wt + (size_t)(cbase + j * 16 + c15) * DM + kk + g * 8);
    for (int i = 0; i < 2; i++)
      for (int j = 0; j < 2; j++)
        acc[i][j] = __builtin_amdgcn_mfma_f32_16x16x32_bf16(a[i], bb[j], acc[i][j], 0, 0, 0);
  }

  for (int i = 0; i < 2; i++)
    for (int j = 0; j < 2; j++) {
      int n = cbase + j * 16 + c15;
      float bv_ = bias[n];
      for (int r = 0; r < 4; r++) {
        int sl = wr * 32 + i * 16 + g * 4 + r;
        int cl = wc * 32 + j * 16 + c15;
        tile[sl][cl] = f2bf(acc[i][j][r] + bv_);
      }
    }
  __syncthreads();

  int R0 = rtb * 64;
  if (ctb < 2) {
    unsigned short* dst = (ctb == 0) ? qws : kws;
    for (int q = 0; q < 2; q++) {
      int rid = q * 256 + tid;
      int sl = rid >> 3, grp = rid & 7;
      bf16x8 vdat = *(const bf16x8*)&tile[sl][grp * 8];
      *(bf16x8*)(dst + (size_t)(R0 + sl) * DA + grp * 8) = vdat;
    }
  } else {
    int bb_ = R0 >> 12, sb = R0 & (SEQ - 1);
    for (int q = 0; q < 2; q++) {
      int rid = q * 256 + tid;
      int dvl = rid >> 3, sub = rid & 7, chunk = sub >> 2, gg = sub & 3;
      union { unsigned short u[8]; bf16x8 h8; } pk;
      for (int j = 0; j < 8; j++) {
        int keyc = (j < 4) ? (4 * gg + j) : (16 + 4 * gg + (j - 4));
        pk.u[j] = tile[chunk * 32 + keyc][dvl];
      }
      int dv = ctb * 64 - 128 + dvl;
      *(bf16x8*)(vt + ((size_t)bb_ * DM + dv) * SEQ + sb + chunk * 32 + gg * 8) = pk.h8;
    }
  }
}

// ------------- Kernel 4: causal flash attention, LDS-staged, KVBLK=64, 32 rows/wave -------------
// Grid (8,64): x=(b,dh); y->qblk (light/heavy halves). Block 256 = 4 waves =
// (rh: 32-row half) x (wc: 128-dv half). Each wave: 2 row-tiles share every K/V LDS read.
__launch_bounds__(256, 2)
__global__ void attn_kernel(const unsigned short* __restrict__ qws,
                            const unsigned short* __restrict__ kws,
                            const unsigned short* __restrict__ vt,
                            unsigned short* __restrict__ ob16) {
  int bd = blockIdx.x;
  int b = bd >> 1, dh = bd & 1;
  int y = blockIdx.y;
  int qblk = (y < 32) ? y : 95 - y;
  int qb = qblk * 64;
  int tid = threadIdx.x;
  int wid = tid >> 6, lane = tid & 63;
  int g = lane >> 4, c15 = lane & 15;
  int rh = wid & 1, wc = wid >> 1;
  int qrow32 = qb + rh * 32;
  int dvb = dh * 256 + wc * 128;
  int wc128 = wc * 128;
  int qsrc = 20 * g;      // lane qsrc+r holds softmax stats for q-row 4g+r

  // 2 x (V[256][64] 32KB + K[64][64] 8KB) = 80KB
  __shared__ unsigned short lds[40960];

  size_t bS = (size_t)b * SEQ;
  int row0 = tid >> 3, c8x = (tid & 7) ^ (row0 & 7);
  const unsigned short* srcV = vt + ((size_t)(b * DM + dh * 256 + row0)) * SEQ + c8x * 8;
  const unsigned short* srcK = kws + (bS + row0) * DA + c8x * 8;

  auto stage = [&](int t, int kt) {
    unsigned short* Vb = &lds[t * 20480];
    unsigned short* Kb = &lds[t * 20480 + 16384];
    for (int r = 0; r < 8; r++)
      g2lds16(srcV + (size_t)(r * 32) * SEQ + kt, &Vb[r * 2048 + wid * 512]);
    for (int r = 0; r < 2; r++)
      g2lds16(srcK + (size_t)(r * 32 + kt) * DA, &Kb[r * 2048 + wid * 512]);
  };

  bf16x8 qf[2][2];
  for (int t2 = 0; t2 < 2; t2++)
    for (int kc = 0; kc < 2; kc++)
      qf[t2][kc] = *(const bf16x8*)(qws + (bS + qrow32 + t2 * 16 + c15) * DA + kc * 32 + g * 8);

  f32x4 acc[2][8];
  for (int t2 = 0; t2 < 2; t2++)
    for (int n = 0; n < 8; n++) acc[t2][n] = (f32x4)0.0f;
  float m_run[2] = {-1e30f, -1e30f}, l_run[2] = {0.0f, 0.0f};

  int nkt = qblk + 1;

  stage(0, 0);
  __syncthreads();
  int t = 0;
  for (int i = 0; i < nkt; i++) {
    int kt = i * 64;
    if (i + 1 < nkt) stage(t ^ 1, kt + 64);
    const unsigned short* Vb = &lds[t * 20480];
    const unsigned short* Kb = &lds[t * 20480 + 16384];
    int sw = c15 & 7;

    // ---- S^T: 64 keys x 32 q-rows (2 tiles share each K read) ----
    f32x4 sc[2][4];
#pragma unroll
    for (int t2 = 0; t2 < 2; t2++)
#pragma unroll
      for (int ct = 0; ct < 4; ct++) sc[t2][ct] = (f32x4)0.0f;
    __builtin_amdgcn_s_setprio(1);
#pragma unroll
    for (int kc = 0; kc < 2; kc++)
#pragma unroll
      for (int ct = 0; ct < 4; ct++) {
        int row = ct * 16 + c15;
        bf16x8 kf = *(const bf16x8*)&Kb[row * 64 + (((kc << 2) | g) ^ sw) * 8];
        sc[0][ct] = __builtin_amdgcn_mfma_f32_16x16x32_bf16(kf, qf[0][kc], sc[0][ct], 0, 0, 0);
        sc[1][ct] = __builtin_amdgcn_mfma_f32_16x16x32_bf16(kf, qf[1][kc], sc[1][ct], 0, 0, 0);
      }
    __builtin_amdgcn_s_setprio(0);

    if (i == nkt - 1) {
#pragma unroll
      for (int t2 = 0; t2 < 2; t2++) {
        int qrow = qrow32 + t2 * 16 + c15;
#pragma unroll
        for (int ct = 0; ct < 4; ct++)
#pragma unroll
          for (int r = 0; r < 4; r++)
            if (kt + ct * 16 + 4 * g + r > qrow) sc[t2][ct][r] = -1e30f;
      }
    }

    // ---- softmax + P pack (per row-tile) ----
    bf16x8 pa[2][2];
#pragma unroll
    for (int t2 = 0; t2 < 2; t2++) {
      float mv = -1e30f;
#pragma unroll
      for (int ct = 0; ct < 4; ct++)
#pragma unroll
        for (int r = 0; r < 4; r++) mv = fmaxf(mv, sc[t2][ct][r]);
      mv = fmaxf(mv, __shfl_xor(mv, 16));
      mv = fmaxf(mv, __shfl_xor(mv, 32));
      float mn = fmaxf(m_run[t2], mv);
      float sum = 0.0f;
#pragma unroll
      for (int ct = 0; ct < 4; ct++)
#pragma unroll
        for (int r = 0; r < 4; r++) {
          float p = __expf(sc[t2][ct][r] - mn);
          sc[t2][ct][r] = p;
          sum += p;
        }
      sum += __shfl_xor(sum, 16);
      sum += __shfl_xor(sum, 32);
      float scl = __expf(m_run[t2] - mn);
      m_run[t2] = mn;
      l_run[t2] = l_run[t2] * scl + sum;
      float s0 = __shfl(scl, qsrc), s1 = __shfl(scl, qsrc + 1);
      float s2 = __shfl(scl, qsrc + 2), s3 = __shfl(scl, qsrc + 3);
#pragma unroll
      for (int n = 0; n < 8; n++) {
        acc[t2][n][0] *= s0; acc[t2][n][1] *= s1;
        acc[t2][n][2] *= s2; acc[t2][n][3] *= s3;
      }
#pragma unroll
      for (int kc = 0; kc < 2; kc++) {
        union { int i4[4]; bf16x8 h; } pu;
        pu.i4[0] = cvt_pk_bf16(sc[t2][2 * kc][0], sc[t2][2 * kc][1]);
        pu.i4[1] = cvt_pk_bf16(sc[t2][2 * kc][2], sc[t2][2 * kc][3]);
        pu.i4[2] = cvt_pk_bf16(sc[t2][2 * kc + 1][0], sc[t2][2 * kc + 1][1]);
        pu.i4[3] = cvt_pk_bf16(sc[t2][2 * kc + 1][2], sc[t2][2 * kc + 1][3]);
        pa[t2][kc] = pu.h;
      }
    }

    // ---- PV: both row-tiles share each V read ----
    __builtin_amdgcn_s_setprio(1);
#pragma unroll
    for (int kc = 0; kc < 2; kc++)
#pragma unroll
      for (int n = 0; n < 8; n++) {
        int row = wc128 + n * 16 + c15;
        bf16x8 vb = *(const bf16x8*)&Vb[row * 64 + (((kc << 2) | g) ^ sw) * 8];
        acc[0][n] = __builtin_amdgcn_mfma_f32_16x16x32_bf16(pa[0][kc], vb, acc[0][n], 0, 0, 0);
        acc[1][n] = __builtin_amdgcn_mfma_f32_16x16x32_bf16(pa[1][kc], vb, acc[1][n], 0, 0, 0);
      }
    __builtin_amdgcn_s_setprio(0);
    __syncthreads();
    t ^= 1;
  }

  // ---- epilogue: O = acc / l, bf16 ----
#pragma unroll
  for (int t2 = 0; t2 < 2; t2++) {
    float inv[4];
#pragma unroll
    for (int r = 0; r < 4; r++) inv[r] = 1.0f / __shfl(l_run[t2], qsrc + r);
#pragma unroll
    for (int n = 0; n < 8; n++)
#pragma unroll
      for (int r = 0; r < 4; r++)
        ob16[(bS + qrow32 + t2 * 16 + 4 * g + r) * DM + dvb + n * 16 + c15] =
            f2bf(acc[t2][n][r] * inv[r]);
  }
}

// ------------- Kernel 5: residual + LayerNorm (wave per row, bf16 o) -------------
__launch_bounds__(256)
__global__ void ln_kernel(const float* __restrict__ x, const unsigned short* __restrict__ o,
                          const float* __restrict__ gamma, const float* __restrict__ beta,
                          float* __restrict__ out) {
  int wid = threadIdx.x >> 6, lane = threadIdx.x & 63;
  size_t row = (size_t)blockIdx.x * 4 + wid;
  size_t base = row * DM + lane * 8;
  float4 xa = *(const float4*)(x + base);
  float4 xb2 = *(const float4*)(x + base + 4);
  bf16x8 ov = *(const bf16x8*)(o + base);
  float y[8] = {xa.x + bf2f((unsigned short)ov[0]), xa.y + bf2f((unsigned short)ov[1]),
                xa.z + bf2f((unsigned short)ov[2]), xa.w + bf2f((unsigned short)ov[3]),
                xb2.x + bf2f((unsigned short)ov[4]), xb2.y + bf2f((unsigned short)ov[5]),
                xb2.z + bf2f((unsigned short)ov[6]), xb2.w + bf2f((unsigned short)ov[7])};
  float s1 = 0.0f, s2 = 0.0f;
  for (int j = 0; j < 8; j++) { s1 += y[j]; s2 += y[j] * y[j]; }
  for (int m = 1; m < 64; m <<= 1) { s1 += __shfl_xor(s1, m); s2 += __shfl_xor(s2, m); }
  float mu = s1 * (1.0f / DM);
  float var = s2 * (1.0f / DM) - mu * mu;
  float rs = rsqrtf(var + 1e-5f);
  int c = lane * 8;
  for (int j = 0; j < 8; j++)
    out[base + j] = (y[j] - mu) * rs * gamma[c + j] + beta[c + j];
}

extern "C" void kernel_launch(void* const* d_in, const int* in_sizes, int n_in,
                              void* d_out, int out_size, void* d_ws, size_t ws_size,
                              hipStream_t stream) {
  const float* x     = (const float*)d_in[0];
  const float* Wq    = (const float*)d_in[1];
  const float* bq    = (const float*)d_in[2];
  const float* Wk    = (const float*)d_in[3];
  const float* bk    = (const float*)d_in[4];
  const float* Wv    = (const float*)d_in[5];
  const float* bv    = (const float*)d_in[6];
  const float* gamma = (const float*)d_in[7];
  const float* beta  = (const float*)d_in[8];
  float* out = (float*)d_out;

  char* ws = (char*)d_ws;
  // ob16 (bf16, 16MB) aliases xb (bf16, 16MB): xb dead before attn writes o.
  unsigned short* xb   = (unsigned short*)(ws + 0);
  unsigned short* ob16 = (unsigned short*)(ws + 0);
  unsigned short* qws  = (unsigned short*)(ws + 16777216);
  unsigned short* kws  = (unsigned short*)(ws + 18874368);
  unsigned short* vt   = (unsigned short*)(ws + 20971520);
  unsigned short* Wt   = (unsigned short*)(ws + 37748736);
  float*          bias = (float*)(ws + 38404096);

  cast_x_kernel<<<8192, 256, 0, stream>>>(x, xb);
  prep_w_kernel<<<640, 256, 0, stream>>>(Wq, bq, Wk, bk, Wv, bv, Wt, bias);
  proj_kernel<<<dim3(10, 256), 256, 0, stream>>>(xb, Wt, bias, qws, kws, vt);
  attn_kernel<<<dim3(8, 64), 256, 0, stream>>>(qws, kws, vt, ob16);
  ln_kernel<<<4096, 256, 0, stream>>>(x, ob16, gamma, beta, out);
}

// Round 7
// 204.082 us; speedup vs baseline: 1.2891x; 1.0942x over previous
//
#include <hip/hip_runtime.h>

#define NB 4
#define SEQ 4096
#define DM 512
#define DA 64

typedef __attribute__((ext_vector_type(8))) short bf16x8;
typedef __attribute__((ext_vector_type(4))) float f32x4;
typedef __attribute__((ext_vector_type(16))) float f32x16;
typedef __attribute__((address_space(3))) unsigned int lds_u32;
typedef const __attribute__((address_space(1))) unsigned int glb_u32;

__device__ __forceinline__ unsigned short f2bf(float f) {
  unsigned u = __float_as_uint(f);
  u += 0x7fffu + ((u >> 16) & 1u);
  return (unsigned short)(u >> 16);
}

__device__ __forceinline__ float bf2f(unsigned short h) {
  return __uint_as_float(((unsigned)h) << 16);
}

__device__ __forceinline__ unsigned cvt_pk_bf16(float lo, float hi) {
  unsigned r;
  asm("v_cvt_pk_bf16_f32 %0, %1, %2" : "=v"(r) : "v"(lo), "v"(hi));
  return r;
}

__device__ __forceinline__ void g2lds16(const unsigned short* g, unsigned short* l) {
  __builtin_amdgcn_global_load_lds((glb_u32*)g, (lds_u32*)l, 16, 0, 0);
}

// ---------------- Kernel 1: cast x (f32) -> xb (bf16) ----------------
__global__ void cast_x_kernel(const float* __restrict__ x, unsigned short* __restrict__ xb) {
  size_t i = ((size_t)blockIdx.x * blockDim.x + threadIdx.x) * 4;
  float4 v = *(const float4*)(x + i);
  ushort4 o;
  o.x = f2bf(v.x); o.y = f2bf(v.y); o.z = f2bf(v.z); o.w = f2bf(v.w);
  *(ushort4*)(xb + i) = o;
}

// ------------- Kernel 2: build Wt[640][512] bf16 (transposed) + bias[640] -------------
__global__ void prep_w_kernel(const float* __restrict__ Wq, const float* __restrict__ bq,
                              const float* __restrict__ Wk, const float* __restrict__ bk,
                              const float* __restrict__ Wv, const float* __restrict__ bv,
                              unsigned short* __restrict__ Wt, float* __restrict__ bias) {
  int n = blockIdx.x;  // 0..639
  for (int k = threadIdx.x; k < DM; k += blockDim.x) {
    float w;
    if (n < 64)       w = Wq[(size_t)k * DA + n];
    else if (n < 128) w = Wk[(size_t)k * DA + (n - 64)];
    else              w = Wv[(size_t)k * DM + (n - 128)];
    Wt[(size_t)n * DM + k] = f2bf(w);
  }
  if (threadIdx.x == 0)
    bias[n] = (n < 64) ? bq[n] : (n < 128) ? bk[n - 64] : bv[n - 128];
}

// ------------- Kernel 3: projection GEMM with LDS-repacked coalesced stores -------------
// n<64 -> q[S][64], n<128 -> k[S][64], else vt[512][SEQ] = V^T with key bits2<->3
// swapped within each 16-key chunk (matches 32x32 MFMA S^T reg->key order).
__launch_bounds__(256)
__global__ void proj_kernel(const unsigned short* __restrict__ xb,
                            const unsigned short* __restrict__ Wt,
                            const float* __restrict__ bias,
                            unsigned short* __restrict__ qws,
                            unsigned short* __restrict__ kws,
                            unsigned short* __restrict__ vt) {
  int ctb = blockIdx.x;
  int rtb = blockIdx.y;
  int tid = threadIdx.x;
  int wid = tid >> 6, lane = tid & 63;
  int g = lane >> 4, c15 = lane & 15;
  int wr = wid >> 1, wc = wid & 1;
  int rbase = rtb * 64 + wr * 32;
  int cbase = ctb * 64 + wc * 32;

  __shared__ unsigned short tile[64][72];

  f32x4 acc[2][2];
  for (int i = 0; i < 2; i++) for (int j = 0; j < 2; j++) acc[i][j] = (f32x4)0.0f;

  for (int kk = 0; kk < DM; kk += 32) {
    bf16x8 a[2], bb[2];
    for (int i = 0; i < 2; i++)
      a[i] = *(const bf16x8*)(xb + (size_t)(rbase + i * 16 + c15) * DM + kk + g * 8);
    for (int j = 0; j < 2; j++)
      bb[j] = *(const bf16x8*)(Wt + (size_t)(cbase + j * 16 + c15) * DM + kk + g * 8);
    for (int i = 0; i < 2; i++)
      for (int j = 0; j < 2; j++)
        acc[i][j] = __builtin_amdgcn_mfma_f32_16x16x32_bf16(a[i], bb[j], acc[i][j], 0, 0, 0);
  }

  for (int i = 0; i < 2; i++)
    for (int j = 0; j < 2; j++) {
      int n = cbase + j * 16 + c15;
      float bv_ = bias[n];
      for (int r = 0; r < 4; r++) {
        int sl = wr * 32 + i * 16 + g * 4 + r;
        int cl = wc * 32 + j * 16 + c15;
        tile[sl][cl] = f2bf(acc[i][j][r] + bv_);
      }
    }
  __syncthreads();

  int R0 = rtb * 64;
  if (ctb < 2) {
    unsigned short* dst = (ctb == 0) ? qws : kws;
    for (int q2 = 0; q2 < 2; q2++) {
      int rid = q2 * 256 + tid;
      int sl = rid >> 3, grp = rid & 7;
      bf16x8 vdat = *(const bf16x8*)&tile[sl][grp * 8];
      *(bf16x8*)(dst + (size_t)(R0 + sl) * DA + grp * 8) = vdat;
    }
  } else {
    int bb_ = R0 >> 12, sb = R0 & (SEQ - 1);
    for (int q2 = 0; q2 < 2; q2++) {
      int rid = q2 * 256 + tid;
      int dvl = rid >> 3, h = rid & 7;
      union { unsigned short u[8]; bf16x8 h8; } pk;
      for (int j = 0; j < 8; j++) {
        int p = h * 8 + j;  // output key-pos
        int s = (p & ~15) | (p & 3) | ((p & 4) << 1) | ((p & 8) >> 1);  // source key
        pk.u[j] = tile[s][dvl];
      }
      int dv = ctb * 64 - 128 + dvl;
      *(bf16x8*)(vt + ((size_t)bb_ * DM + dv) * SEQ + sb + h * 8) = pk.h8;
    }
  }
}

// ------------- Kernel 4: causal flash attention, 32x32 MFMA, LDS-staged -------------
// Grid (16,32): x = 4b+dvc (XCD L2-affine: K+V slice ~3MB fits per-XCD L2);
// y -> qblk paired light/heavy. Block 256 thr = 4 waves = 4 distinct 32-row groups.
// Wave: 32q x 128dv. S^T = mfma(K,Q) 32x32: lane owns q=lane&31, 32 in-lane
// scores, softmax = in-lane + 1 shfl_xor(32). P packed (cvt_pk) feeds PV B-frag
// in reg order (V keys bit2<->3 pre-swapped). KVBLK=64, dbuf LDS 48KB.
__launch_bounds__(256, 2)
__global__ void attn_kernel(const unsigned short* __restrict__ qws,
                            const unsigned short* __restrict__ kws,
                            const unsigned short* __restrict__ vt,
                            unsigned short* __restrict__ ob16) {
  int xx = blockIdx.x;
  int b = xx >> 2, dvc = xx & 3;
  int dvb = dvc * 128;
  int y = blockIdx.y;
  int qblk = (y < 16) ? y : 47 - y;
  int qb = qblk * 128;
  int tid = threadIdx.x;
  int wid = tid >> 6, lane = tid & 63;
  int l31 = lane & 31, lh = lane >> 5;
  int qrow32 = qb + wid * 32;

  // 2 x (V 128x64 = 8192 ush | K 64x64 = 4096 ush) = 24576 ush = 48KB
  __shared__ unsigned short lds[24576];

  size_t bS = (size_t)b * SEQ;
  int srow = tid >> 3;                       // 0..31
  int scol = (tid & 7) ^ (srow & 7);         // pre-swizzled source slot
  const unsigned short* srcV = vt + ((size_t)(b * DM + dvb + srow)) * SEQ + scol * 8;
  const unsigned short* srcK = kws + (bS + srow) * DA + scol * 8;

  auto stage = [&](int t, int kt) {
    unsigned short* Vb = &lds[t * 12288];
    unsigned short* Kb = &lds[t * 12288 + 8192];
    for (int r = 0; r < 4; r++)
      g2lds16(srcV + (size_t)(r * 32) * SEQ + kt, &Vb[r * 2048 + wid * 512]);
    for (int r = 0; r < 2; r++)
      g2lds16(srcK + (size_t)(kt + r * 32) * DA, &Kb[r * 2048 + wid * 512]);
  };

  // Q B-frags: lane holds Q[qrow32 + l31][16c + lh*8 .. +8]
  bf16x8 qf[4];
#pragma unroll
  for (int c = 0; c < 4; c++)
    qf[c] = *(const bf16x8*)(qws + (bS + qrow32 + l31) * DA + c * 16 + lh * 8);

  f32x16 acc[4];
#pragma unroll
  for (int dt = 0; dt < 4; dt++) acc[dt] = (f32x16)0.0f;
  float m_run = -1e30f, l_run = 0.0f;

  int nkt = 2 * qblk + 2;

  stage(0, 0);
  __syncthreads();
  int t = 0;
  for (int i = 0; i < nkt; i++) {
    int kt = i * 64;
    if (i + 1 < nkt) stage(t ^ 1, kt + 64);
    const unsigned short* Vb = &lds[t * 12288];
    const unsigned short* Kb = &lds[t * 12288 + 8192];

    // ---- S^T: 64 keys x 32 q ----
    f32x16 sc[2];
    sc[0] = (f32x16)0.0f; sc[1] = (f32x16)0.0f;
    __builtin_amdgcn_s_setprio(1);
#pragma unroll
    for (int s2 = 0; s2 < 2; s2++)
#pragma unroll
      for (int c = 0; c < 4; c++) {
        int row = s2 * 32 + l31;
        bf16x8 kf = *(const bf16x8*)&Kb[row * 64 + (((c << 1) | lh) ^ (row & 7)) * 8];
        sc[s2] = __builtin_amdgcn_mfma_f32_32x32x16_bf16(kf, qf[c], sc[s2], 0, 0, 0);
      }
    __builtin_amdgcn_s_setprio(0);

    if (kt + 63 > qrow32) {  // wave-uniform: only tiles crossing the diagonal
      int qrow = qrow32 + l31;
#pragma unroll
      for (int s2 = 0; s2 < 2; s2++)
#pragma unroll
        for (int p = 0; p < 16; p++) {
          int key = kt + s2 * 32 + (p & 3) + 8 * (p >> 2) + 4 * lh;
          if (key > qrow) sc[s2][p] = -1e30f;
        }
    }

    // ---- softmax: 32 in-lane + 1 shfl ----
    float mv = -1e30f;
#pragma unroll
    for (int s2 = 0; s2 < 2; s2++)
#pragma unroll
      for (int p = 0; p < 16; p++) mv = fmaxf(mv, sc[s2][p]);
    mv = fmaxf(mv, __shfl_xor(mv, 32));
    float mn = fmaxf(m_run, mv);
    float sum = 0.0f;
#pragma unroll
    for (int s2 = 0; s2 < 2; s2++)
#pragma unroll
      for (int p = 0; p < 16; p++) {
        float pe = __expf(sc[s2][p] - mn);
        sc[s2][p] = pe;
        sum += pe;
      }
    sum += __shfl_xor(sum, 32);
    float scl = __expf(m_run - mn);
    m_run = mn;
    l_run = l_run * scl + sum;
#pragma unroll
    for (int dt = 0; dt < 4; dt++)
#pragma unroll
      for (int p = 0; p < 16; p++) acc[dt][p] *= scl;

    // ---- pack P: chunk c regs = sc[c>>1][(c&1)*8 .. +8] ----
    bf16x8 pa[4];
#pragma unroll
    for (int c = 0; c < 4; c++) {
      union { unsigned u[4]; bf16x8 h; } pu;
      int s2 = c >> 1, o = (c & 1) * 8;
      pu.u[0] = cvt_pk_bf16(sc[s2][o + 0], sc[s2][o + 1]);
      pu.u[1] = cvt_pk_bf16(sc[s2][o + 2], sc[s2][o + 3]);
      pu.u[2] = cvt_pk_bf16(sc[s2][o + 4], sc[s2][o + 5]);
      pu.u[3] = cvt_pk_bf16(sc[s2][o + 6], sc[s2][o + 7]);
      pa[c] = pu.h;
    }

    // ---- PV: O^T[dv][q] += V^T-frag x P-frag ----
    __builtin_amdgcn_s_setprio(1);
#pragma unroll
    for (int c = 0; c < 4; c++)
#pragma unroll
      for (int dt = 0; dt < 4; dt++) {
        int row = dt * 32 + l31;
        bf16x8 vb = *(const bf16x8*)&Vb[row * 64 + (((c << 1) | lh) ^ (row & 7)) * 8];
        acc[dt] = __builtin_amdgcn_mfma_f32_32x32x16_bf16(vb, pa[c], acc[dt], 0, 0, 0);
      }
    __builtin_amdgcn_s_setprio(0);
    __syncthreads();
    t ^= 1;
  }

  // ---- epilogue: O^T -> per-wave LDS transpose -> coalesced bf16 store ----
  float inv = 1.0f / l_run;
  unsigned short* Ob = &lds[wid * 4224];   // 32 rows x 132
#pragma unroll
  for (int dt = 0; dt < 4; dt++)
#pragma unroll
    for (int j = 0; j < 8; j++) {
      int p = 2 * j;
      int dv = dt * 32 + (p & 3) + 8 * (p >> 2) + 4 * lh;
      unsigned pk = cvt_pk_bf16(acc[dt][p] * inv, acc[dt][p + 1] * inv);
      *(unsigned*)&Ob[l31 * 132 + dv] = pk;
    }
  __syncthreads();
#pragma unroll
  for (int k = 0; k < 8; k++) {
    int row = lane >> 1, dvh = (lane & 1) * 64;
    bf16x8 o8 = *(const bf16x8*)&Ob[row * 132 + dvh + k * 8];
    *(bf16x8*)(ob16 + (bS + qrow32 + row) * DM + dvb + dvh + k * 8) = o8;
  }
}

// ------------- Kernel 5: residual + LayerNorm (wave per row, bf16 o) -------------
__launch_bounds__(256)
__global__ void ln_kernel(const float* __restrict__ x, const unsigned short* __restrict__ o,
                          const float* __restrict__ gamma, const float* __restrict__ beta,
                          float* __restrict__ out) {
  int wid = threadIdx.x >> 6, lane = threadIdx.x & 63;
  size_t row = (size_t)blockIdx.x * 4 + wid;
  size_t base = row * DM + lane * 8;
  float4 xa = *(const float4*)(x + base);
  float4 xb2 = *(const float4*)(x + base + 4);
  bf16x8 ov = *(const bf16x8*)(o + base);
  float y[8] = {xa.x + bf2f((unsigned short)ov[0]), xa.y + bf2f((unsigned short)ov[1]),
                xa.z + bf2f((unsigned short)ov[2]), xa.w + bf2f((unsigned short)ov[3]),
                xb2.x + bf2f((unsigned short)ov[4]), xb2.y + bf2f((unsigned short)ov[5]),
                xb2.z + bf2f((unsigned short)ov[6]), xb2.w + bf2f((unsigned short)ov[7])};
  float s1 = 0.0f, s2 = 0.0f;
  for (int j = 0; j < 8; j++) { s1 += y[j]; s2 += y[j] * y[j]; }
  for (int m = 1; m < 64; m <<= 1) { s1 += __shfl_xor(s1, m); s2 += __shfl_xor(s2, m); }
  float mu = s1 * (1.0f / DM);
  float var = s2 * (1.0f / DM) - mu * mu;
  float rs = rsqrtf(var + 1e-5f);
  int c = lane * 8;
  for (int j = 0; j < 8; j++)
    out[base + j] = (y[j] - mu) * rs * gamma[c + j] + beta[c + j];
}

extern "C" void kernel_launch(void* const* d_in, const int* in_sizes, int n_in,
                              void* d_out, int out_size, void* d_ws, size_t ws_size,
                              hipStream_t stream) {
  const float* x     = (const float*)d_in[0];
  const float* Wq    = (const float*)d_in[1];
  const float* bq    = (const float*)d_in[2];
  const float* Wk    = (const float*)d_in[3];
  const float* bk    = (const float*)d_in[4];
  const float* Wv    = (const float*)d_in[5];
  const float* bv    = (const float*)d_in[6];
  const float* gamma = (const float*)d_in[7];
  const float* beta  = (const float*)d_in[8];
  float* out = (float*)d_out;

  char* ws = (char*)d_ws;
  // ob16 (bf16, 16MB) aliases xb (bf16, 16MB): xb dead before attn writes o.
  unsigned short* xb   = (unsigned short*)(ws + 0);
  unsigned short* ob16 = (unsigned short*)(ws + 0);
  unsigned short* qws  = (unsigned short*)(ws + 16777216);
  unsigned short* kws  = (unsigned short*)(ws + 18874368);
  unsigned short* vt   = (unsigned short*)(ws + 20971520);
  unsigned short* Wt   = (unsigned short*)(ws + 37748736);
  float*          bias = (float*)(ws + 38404096);

  cast_x_kernel<<<8192, 256, 0, stream>>>(x, xb);
  prep_w_kernel<<<640, 256, 0, stream>>>(Wq, bq, Wk, bk, Wv, bv, Wt, bias);
  proj_kernel<<<dim3(10, 256), 256, 0, stream>>>(xb, Wt, bias, qws, kws, vt);
  attn_kernel<<<dim3(16, 32), 256, 0, stream>>>(qws, kws, vt, ob16);
  ln_kernel<<<4096, 256, 0, stream>>>(x, ob16, gamma, beta, out);
}

// Round 8
// 182.469 us; speedup vs baseline: 1.4418x; 1.1184x over previous
//
#include <hip/hip_runtime.h>

#define NB 4
#define SEQ 4096
#define DM 512
#define DA 64

typedef __attribute__((ext_vector_type(8))) short bf16x8;
typedef __attribute__((ext_vector_type(4))) float f32x4;
typedef __attribute__((ext_vector_type(16))) float f32x16;

__device__ __forceinline__ unsigned short f2bf(float f) {
  unsigned u = __float_as_uint(f);
  u += 0x7fffu + ((u >> 16) & 1u);
  return (unsigned short)(u >> 16);
}

__device__ __forceinline__ float bf2f(unsigned short h) {
  return __uint_as_float(((unsigned)h) << 16);
}

__device__ __forceinline__ unsigned cvt_pk_bf16(float lo, float hi) {
  unsigned r;
  asm("v_cvt_pk_bf16_f32 %0, %1, %2" : "=v"(r) : "v"(lo), "v"(hi));
  return r;
}

// ---------------- Kernel 1: cast x (f32) -> xb (bf16) ----------------
__global__ void cast_x_kernel(const float* __restrict__ x, unsigned short* __restrict__ xb) {
  size_t i = ((size_t)blockIdx.x * blockDim.x + threadIdx.x) * 4;
  float4 v = *(const float4*)(x + i);
  ushort4 o;
  o.x = f2bf(v.x); o.y = f2bf(v.y); o.z = f2bf(v.z); o.w = f2bf(v.w);
  *(ushort4*)(xb + i) = o;
}

// ------------- Kernel 2: build Wt[640][512] bf16 (transposed) + bias[640] -------------
__global__ void prep_w_kernel(const float* __restrict__ Wq, const float* __restrict__ bq,
                              const float* __restrict__ Wk, const float* __restrict__ bk,
                              const float* __restrict__ Wv, const float* __restrict__ bv,
                              unsigned short* __restrict__ Wt, float* __restrict__ bias) {
  int n = blockIdx.x;  // 0..639
  for (int k = threadIdx.x; k < DM; k += blockDim.x) {
    float w;
    if (n < 64)       w = Wq[(size_t)k * DA + n];
    else if (n < 128) w = Wk[(size_t)k * DA + (n - 64)];
    else              w = Wv[(size_t)k * DM + (n - 128)];
    Wt[(size_t)n * DM + k] = f2bf(w);
  }
  if (threadIdx.x == 0)
    bias[n] = (n < 64) ? bq[n] : (n < 128) ? bk[n - 64] : bv[n - 128];
}

// ------------- Kernel 3: projection GEMM, outputs in MFMA-fragment-native layouts -----
// ctb0 -> q[S][64]; ctb1 -> K'[b][ktc][slot][key][8]; ctb2..9 -> V'[b][dvc][ktc][slot][dvrow][8]
// V' stores key kappa(slot,j) at position j so attn's PV B-frag works in register order.
__launch_bounds__(256)
__global__ void proj_kernel(const unsigned short* __restrict__ xb,
                            const unsigned short* __restrict__ Wt,
                            const float* __restrict__ bias,
                            unsigned short* __restrict__ qws,
                            unsigned short* __restrict__ kp,
                            unsigned short* __restrict__ vp) {
  int ctb = blockIdx.x;
  int rtb = blockIdx.y;
  int tid = threadIdx.x;
  int wid = tid >> 6, lane = tid & 63;
  int g = lane >> 4, c15 = lane & 15;
  int wr = wid >> 1, wc = wid & 1;
  int rbase = rtb * 64 + wr * 32;
  int cbase = ctb * 64 + wc * 32;

  __shared__ unsigned short tile[64][72];

  f32x4 acc[2][2];
  for (int i = 0; i < 2; i++) for (int j = 0; j < 2; j++) acc[i][j] = (f32x4)0.0f;

  for (int kk = 0; kk < DM; kk += 32) {
    bf16x8 a[2], bb[2];
    for (int i = 0; i < 2; i++)
      a[i] = *(const bf16x8*)(xb + (size_t)(rbase + i * 16 + c15) * DM + kk + g * 8);
    for (int j = 0; j < 2; j++)
      bb[j] = *(const bf16x8*)(Wt + (size_t)(cbase + j * 16 + c15) * DM + kk + g * 8);
    for (int i = 0; i < 2; i++)
      for (int j = 0; j < 2; j++)
        acc[i][j] = __builtin_amdgcn_mfma_f32_16x16x32_bf16(a[i], bb[j], acc[i][j], 0, 0, 0);
  }

  for (int i = 0; i < 2; i++)
    for (int j = 0; j < 2; j++) {
      int n = cbase + j * 16 + c15;
      float bv_ = bias[n];
      for (int r = 0; r < 4; r++) {
        int sl = wr * 32 + i * 16 + g * 4 + r;
        int cl = wc * 32 + j * 16 + c15;
        tile[sl][cl] = f2bf(acc[i][j][r] + bv_);
      }
    }
  __syncthreads();

  int R0 = rtb * 64;
  int b = R0 >> 12, ktc = (R0 & (SEQ - 1)) >> 6;
  if (ctb == 0) {
    for (int q2 = 0; q2 < 2; q2++) {
      int rid = q2 * 256 + tid;
      int sl = rid >> 3, grp = rid & 7;
      bf16x8 vdat = *(const bf16x8*)&tile[sl][grp * 8];
      *(bf16x8*)(qws + (size_t)(R0 + sl) * DA + grp * 8) = vdat;
    }
  } else if (ctb == 1) {
    // K'[((b*64+ktc)*8 + slot)*64 + key][8] = tile[key][slot*8..+8]
    for (int q2 = 0; q2 < 2; q2++) {
      int rid = q2 * 256 + tid;
      int slot = rid >> 6, key = rid & 63;
      bf16x8 vdat = *(const bf16x8*)&tile[key][slot * 8];
      *(bf16x8*)(kp + ((((size_t)b * 64 + ktc) * 8 + slot) * 64 + key) * 8) = vdat;
    }
  } else {
    for (int q2 = 0; q2 < 2; q2++) {
      int rid = q2 * 256 + tid;
      int slot = rid >> 6, dvl = rid & 63;
      int dv = (ctb - 2) * 64 + dvl;
      int dvc = dv >> 7, dvrow = dv & 127;
      union { unsigned short u[8]; bf16x8 h8; } pk;
      for (int j = 0; j < 8; j++) {
        int key = ((slot >> 2) << 5) | (((slot >> 1) & 1) << 4) | ((j >> 2) << 3) |
                  ((slot & 1) << 2) | (j & 3);
        pk.u[j] = tile[key][dvl];
      }
      *(bf16x8*)(vp + (((((size_t)(b * 4 + dvc)) * 64 + ktc) * 8 + slot) * 128 + dvrow) * 8) = pk.h8;
    }
  }
}

// ------------- Kernel 4: causal flash attention, L2-direct frags, split-K waves -------
// Grid (16, 128): x = b*4+dvc (XCD-affine), y -> strip 127-y (heavy first).
// Block 256 = 4 independent waves over the SAME 32-row q-strip; wave w does kt-tiles
// w, w+4, ... (no barriers in main loop). End: 2-barrier (m,l,A) merge via LDS.
__launch_bounds__(256, 3)
__global__ void attn_kernel(const unsigned short* __restrict__ qws,
                            const unsigned short* __restrict__ kp,
                            const unsigned short* __restrict__ vp,
                            unsigned short* __restrict__ ob16) {
  int x = blockIdx.x, b = x >> 2, dvc = x & 3;
  int strip = 127 - blockIdx.y;
  int qrow32 = strip * 32;
  int n = (strip >> 1) + 1;
  int tid = threadIdx.x, w = tid >> 6, lane = tid & 63;
  int l31 = lane & 31, lh = lane >> 5;

  __shared__ unsigned short abuf[4][32][136];   // bf16 partial A, padded rows
  __shared__ float mbuf[4][32], lbuf[4][32], Lfin[32];

  size_t bS = (size_t)b * SEQ;

  bf16x8 qf[4];
#pragma unroll
  for (int c = 0; c < 4; c++)
    qf[c] = *(const bf16x8*)(qws + (bS + qrow32 + l31) * DA + c * 16 + lh * 8);

  const unsigned short* kbase = kp + (size_t)b * 64 * 4096 + lh * 512 + l31 * 8;
  const unsigned short* vbase = vp + (size_t)(b * 4 + dvc) * 64 * 8192 + lh * 1024 + l31 * 8;

  f32x16 acc[4];
#pragma unroll
  for (int dt = 0; dt < 4; dt++) acc[dt] = (f32x16)0.0f;
  float m_run = -1e30f, l_run = 0.0f;

  for (int t = w; t < n; t += 4) {
    const unsigned short* kt_ = kbase + (size_t)t * 4096;
    const unsigned short* vt_ = vbase + (size_t)t * 8192;

    bf16x8 kf[4][2];
#pragma unroll
    for (int c = 0; c < 4; c++)
#pragma unroll
      for (int s2 = 0; s2 < 2; s2++)
        kf[c][s2] = *(const bf16x8*)(kt_ + c * 1024 + s2 * 256);
    bf16x8 vbA[4];
#pragma unroll
    for (int dt = 0; dt < 4; dt++)
      vbA[dt] = *(const bf16x8*)(vt_ + dt * 256);

    f32x16 sc[2];
    sc[0] = (f32x16)0.0f; sc[1] = (f32x16)0.0f;
    __builtin_amdgcn_s_setprio(1);
#pragma unroll
    for (int c = 0; c < 4; c++)
#pragma unroll
      for (int s2 = 0; s2 < 2; s2++)
        sc[s2] = __builtin_amdgcn_mfma_f32_32x32x16_bf16(kf[c][s2], qf[c], sc[s2], 0, 0, 0);
    __builtin_amdgcn_s_setprio(0);

    if (t == n - 1) {   // only the diagonal tile (wave-uniform)
      int kt = t * 64, qrow = qrow32 + l31;
#pragma unroll
      for (int s2 = 0; s2 < 2; s2++)
#pragma unroll
        for (int p = 0; p < 16; p++) {
          int key = kt + s2 * 32 + (p & 3) + 8 * (p >> 2) + 4 * lh;
          if (key > qrow) sc[s2][p] = -1e30f;
        }
    }

    // ---- softmax: 32 in-lane + 1 shfl ----
    float mv = -1e30f;
#pragma unroll
    for (int s2 = 0; s2 < 2; s2++)
#pragma unroll
      for (int p = 0; p < 16; p++) mv = fmaxf(mv, sc[s2][p]);
    mv = fmaxf(mv, __shfl_xor(mv, 32));
    float mn = fmaxf(m_run, mv);
    float sum = 0.0f;
#pragma unroll
    for (int s2 = 0; s2 < 2; s2++)
#pragma unroll
      for (int p = 0; p < 16; p++) {
        float pe = __expf(sc[s2][p] - mn);
        sc[s2][p] = pe;
        sum += pe;
      }
    sum += __shfl_xor(sum, 32);
    float scl = __expf(m_run - mn);
    m_run = mn;
    l_run = l_run * scl + sum;
#pragma unroll
    for (int dt = 0; dt < 4; dt++)
#pragma unroll
      for (int p = 0; p < 16; p++) acc[dt][p] *= scl;

    bf16x8 pa[4];
#pragma unroll
    for (int c = 0; c < 4; c++) {
      union { unsigned u[4]; bf16x8 h; } pu;
      int s2 = c >> 1, o = (c & 1) * 8;
      pu.u[0] = cvt_pk_bf16(sc[s2][o + 0], sc[s2][o + 1]);
      pu.u[1] = cvt_pk_bf16(sc[s2][o + 2], sc[s2][o + 3]);
      pu.u[2] = cvt_pk_bf16(sc[s2][o + 4], sc[s2][o + 5]);
      pu.u[3] = cvt_pk_bf16(sc[s2][o + 6], sc[s2][o + 7]);
      pa[c] = pu.h;
    }

    __builtin_amdgcn_s_setprio(1);
#pragma unroll
    for (int c = 0; c < 4; c++) {
      bf16x8 vbB[4];
      if (c < 3) {
#pragma unroll
        for (int dt = 0; dt < 4; dt++)
          vbB[dt] = *(const bf16x8*)(vt_ + (c + 1) * 2048 + dt * 256);
      }
#pragma unroll
      for (int dt = 0; dt < 4; dt++)
        acc[dt] = __builtin_amdgcn_mfma_f32_32x32x16_bf16(vbA[dt], pa[c], acc[dt], 0, 0, 0);
      if (c < 3) {
#pragma unroll
        for (int dt = 0; dt < 4; dt++) vbA[dt] = vbB[dt];
      }
    }
    __builtin_amdgcn_s_setprio(0);
  }

  // ---- merge 4 waves' partials ----
  if (lh == 0) { mbuf[w][l31] = m_run; lbuf[w][l31] = l_run; }
  __syncthreads();
  float M = fmaxf(fmaxf(mbuf[0][l31], mbuf[1][l31]), fmaxf(mbuf[2][l31], mbuf[3][l31]));
  float d = __expf(m_run - M);
  float L = lbuf[0][l31] * __expf(mbuf[0][l31] - M) + lbuf[1][l31] * __expf(mbuf[1][l31] - M) +
            lbuf[2][l31] * __expf(mbuf[2][l31] - M) + lbuf[3][l31] * __expf(mbuf[3][l31] - M);
  if (w == 0 && lh == 0) Lfin[l31] = L;
#pragma unroll
  for (int dt = 0; dt < 4; dt++)
#pragma unroll
    for (int p = 0; p < 16; p += 2) {
      int dv = dt * 32 + (p & 3) + 8 * (p >> 2) + 4 * lh;
      *(unsigned*)&abuf[w][l31][dv] = cvt_pk_bf16(acc[dt][p] * d, acc[dt][p + 1] * d);
    }
  __syncthreads();

  int q = w * 8 + (l31 >> 2);
  int ch = (l31 & 3) * 32 + lh * 16;
  float s[16];
#pragma unroll
  for (int k = 0; k < 16; k++) s[k] = 0.0f;
#pragma unroll
  for (int v = 0; v < 4; v++) {
    bf16x8 a0 = *(const bf16x8*)&abuf[v][q][ch];
    bf16x8 a1 = *(const bf16x8*)&abuf[v][q][ch + 8];
#pragma unroll
    for (int k = 0; k < 8; k++) {
      s[k] += bf2f((unsigned short)a0[k]);
      s[8 + k] += bf2f((unsigned short)a1[k]);
    }
  }
  float inv = 1.0f / Lfin[q];
  union { unsigned u[8]; bf16x8 h[2]; } o;
#pragma unroll
  for (int k = 0; k < 8; k++)
    o.u[k] = cvt_pk_bf16(s[2 * k] * inv, s[2 * k + 1] * inv);
  unsigned short* dst = ob16 + (bS + qrow32 + q) * DM + dvc * 128 + ch;
  *(bf16x8*)dst = o.h[0];
  *(bf16x8*)(dst + 8) = o.h[1];
}

// ------------- Kernel 5: residual + LayerNorm (wave per row, bf16 o) -------------
__launch_bounds__(256)
__global__ void ln_kernel(const float* __restrict__ x, const unsigned short* __restrict__ o,
                          const float* __restrict__ gamma, const float* __restrict__ beta,
                          float* __restrict__ out) {
  int wid = threadIdx.x >> 6, lane = threadIdx.x & 63;
  size_t row = (size_t)blockIdx.x * 4 + wid;
  size_t base = row * DM + lane * 8;
  float4 xa = *(const float4*)(x + base);
  float4 xb2 = *(const float4*)(x + base + 4);
  bf16x8 ov = *(const bf16x8*)(o + base);
  float y[8] = {xa.x + bf2f((unsigned short)ov[0]), xa.y + bf2f((unsigned short)ov[1]),
                xa.z + bf2f((unsigned short)ov[2]), xa.w + bf2f((unsigned short)ov[3]),
                xb2.x + bf2f((unsigned short)ov[4]), xb2.y + bf2f((unsigned short)ov[5]),
                xb2.z + bf2f((unsigned short)ov[6]), xb2.w + bf2f((unsigned short)ov[7])};
  float s1 = 0.0f, s2 = 0.0f;
  for (int j = 0; j < 8; j++) { s1 += y[j]; s2 += y[j] * y[j]; }
  for (int m = 1; m < 64; m <<= 1) { s1 += __shfl_xor(s1, m); s2 += __shfl_xor(s2, m); }
  float mu = s1 * (1.0f / DM);
  float var = s2 * (1.0f / DM) - mu * mu;
  float rs = rsqrtf(var + 1e-5f);
  int c = lane * 8;
  for (int j = 0; j < 8; j++)
    out[base + j] = (y[j] - mu) * rs * gamma[c + j] + beta[c + j];
}

extern "C" void kernel_launch(void* const* d_in, const int* in_sizes, int n_in,
                              void* d_out, int out_size, void* d_ws, size_t ws_size,
                              hipStream_t stream) {
  const float* x     = (const float*)d_in[0];
  const float* Wq    = (const float*)d_in[1];
  const float* bq    = (const float*)d_in[2];
  const float* Wk    = (const float*)d_in[3];
  const float* bk    = (const float*)d_in[4];
  const float* Wv    = (const float*)d_in[5];
  const float* bv    = (const float*)d_in[6];
  const float* gamma = (const float*)d_in[7];
  const float* beta  = (const float*)d_in[8];
  float* out = (float*)d_out;

  char* ws = (char*)d_ws;
  // ob16 (bf16, 16MB) aliases xb: xb dead before attn writes o.
  unsigned short* xb   = (unsigned short*)(ws + 0);
  unsigned short* ob16 = (unsigned short*)(ws + 0);
  unsigned short* qws  = (unsigned short*)(ws + 16777216);
  unsigned short* kp   = (unsigned short*)(ws + 18874368);
  unsigned short* vp   = (unsigned short*)(ws + 20971520);
  unsigned short* Wt   = (unsigned short*)(ws + 54525952);
  float*          bias = (float*)(ws + 55181312);

  cast_x_kernel<<<8192, 256, 0, stream>>>(x, xb);
  prep_w_kernel<<<640, 256, 0, stream>>>(Wq, bq, Wk, bk, Wv, bv, Wt, bias);
  proj_kernel<<<dim3(10, 256), 256, 0, stream>>>(xb, Wt, bias, qws, kp, vp);
  attn_kernel<<<dim3(16, 128), 256, 0, stream>>>(qws, kp, vp, ob16);
  ln_kernel<<<4096, 256, 0, stream>>>(x, ob16, gamma, beta, out);
}